// Round 8
// baseline (427.127 us; speedup 1.0000x reference)
//
#include <hip/hip_runtime.h>
#include <math.h>

#define BATCH  16
#define F_IN   16
#define F_OUT  64
#define NGRID  32
#define NSPEC  256
#define NU     136           // triangular (l,m>=0) count
#define NITEMS 496           // (m>=0, n) items
#define NP4    3680          // padded (item,l) count: runs padded to multiple of 4
#define NP4Q   3910          // NP4 + NP4/16 (LDS swizzle expansion)
#define SCALING 0.005524271728019903f
#define PI_F 3.14159265358979323846f
#define W32 0.19634954084936207f   // 2*pi/32

// cof2[l] = c_off[l] + 2l(l+1): wig_so3 offset = cof2[l] + m*(2l+1) + n
__device__ const int d_cof2[16] = {0,5,22,59,124,225,370,567,824,1149,1550,2035,2612,3289,4074,4975};
// PB[lam]: padded base of lam-group; run of item (lam,r) starts at PB[lam] + r*pl(lam), pl = (19-lam)&~3
__device__ const int d_PB[16] = {0,16,96,240,448,652,904,1204,1552,1816,2112,2440,2800,2996,3208,3436};

// decode item t (lam-sorted) -> lam, r, m, n
__device__ __forceinline__ void decode_item(int t, int& lam, int& r, int& m, int& n) {
    lam = (int)sqrtf((float)t * 0.5f);
    while ((2*lam + 1) * (lam + 1) <= t) ++lam;
    while (lam > 0 && (2*lam - 1) * lam > t) --lam;
    r = t - (2*lam - 1) * lam;
    if (r < 2*lam + 1) { m = lam; n = r - lam; }
    else { const int r2 = r - (2*lam + 1); m = r2 >> 1; n = (r2 & 1) ? lam : -lam; }
}

// decode padded index p4 -> l, m, n, valid
__device__ __forceinline__ void decode_p4(int p4, int& l, int& m, int& n, int& valid) {
    int lam = 0;
    #pragma unroll
    for (int q = 1; q < 16; ++q) if (p4 >= d_PB[q]) lam = q;
    const int pl = (19 - lam) & ~3;
    const int q2 = p4 - d_PB[lam];
    int ti = q2 / pl;
    const int j = q2 - ti * pl;
    l = lam + j;
    valid = (j < 16 - lam);
    if (l > 15) l = 15;
    if (ti < 2*lam + 1) { m = lam; n = ti - lam; }
    else { const int r2 = ti - (2*lam + 1); m = r2 >> 1; n = (r2 & 1) ? lam : -lam; }
}

// ---------------- K_prep: k1 (0..255) | k2 (256..511) | wigt4+p4lut (512..626) | itemlut (627..628) ----
__global__ __launch_bounds__(256) void k_prep(const float* __restrict__ x,
                                              const float* __restrict__ wig_s2,
                                              const float* __restrict__ kern,
                                              const float* __restrict__ fk_re,
                                              const float* __restrict__ fk_im,
                                              const float* __restrict__ wig,
                                              float2* __restrict__ fhat,
                                              float2* __restrict__ psic,
                                              float4* __restrict__ wigt4,
                                              unsigned int* __restrict__ p4lut,
                                              unsigned int* __restrict__ itemlut) {
    __shared__ __align__(16) char smem[25088];
    const int blk = blockIdx.x;
    const int tid = threadIdx.x;

    if (blk < 256) {
        // ---- k1: fhat_t[b][u][f] ----
        float (*xs)[65]  = (float (*)[65])smem;            // 64*65*4 = 16640
        float2 (*xf)[65] = (float2 (*)[65])(smem + 16640); // 16*65*8 = 8320
        const int b = blk >> 4, f = blk & 15;

        const float4* src = (const float4*)(x + (size_t)(b * F_IN + f) * 4096);
        for (int t = tid; t < 1024; t += 256) {
            float4 v = src[t];
            const int row = t >> 4, col = (t & 15) * 4;
            xs[row][col] = v.x; xs[row][col+1] = v.y; xs[row][col+2] = v.z; xs[row][col+3] = v.w;
        }
        __syncthreads();
        {
            const int m = tid >> 4, j0 = tid & 15;
            float stc, sts;
            sincosf(-(2.f * PI_F / 64.f) * (float)m, &sts, &stc);
            float wr = 1.f, wi = 0.f;
            float ar[4] = {0,0,0,0}, ai[4] = {0,0,0,0};
            #pragma unroll 8
            for (int a = 0; a < 64; ++a) {
                #pragma unroll
                for (int q = 0; q < 4; ++q) {
                    const float v = xs[j0 + 16*q][a];
                    ar[q] += v * wr; ai[q] += v * wi;
                }
                const float nr = wr*stc - wi*sts; wi = wr*sts + wi*stc; wr = nr;
            }
            #pragma unroll
            for (int q = 0; q < 4; ++q) xf[m][j0 + 16*q] = make_float2(ar[q], ai[q]);
        }
        __syncthreads();
        if (tid < NU) {
            int l = (int)((sqrtf(8.f * (float)tid + 1.f) - 1.f) * 0.5f);
            while ((l + 1) * (l + 2) / 2 <= tid) ++l;
            while (l * (l + 1) / 2 > tid) --l;
            const int m = tid - l * (l + 1) / 2;
            const int s = l * l + l + m;
            float re = 0.f, im = 0.f;
            #pragma unroll 8
            for (int j = 0; j < 64; ++j) {
                const float2 v = xf[m][j];
                const float w = wig_s2[j * NSPEC + s];
                re += v.x * w; im += v.y * w;
            }
            fhat[(b * NU + tid) * F_IN + f] = make_float2(re, im);
        }
    } else if (blk < 512) {
        // ---- k2: psic_t[o][s][i] ----
        float2* fk = (float2*)smem;
        const int s = blk - 256;
        if (tid < NGRID) fk[tid] = make_float2(fk_re[s * NGRID + tid], -fk_im[s * NGRID + tid]);
        __syncthreads();
        for (int t = tid; t < F_OUT * F_IN; t += 256) {
            const int o = t >> 4, i = t & 15;
            const float4* kr = (const float4*)(kern + (size_t)(i * F_OUT + o) * NGRID);
            float re = 0.f, im = 0.f;
            #pragma unroll
            for (int g4 = 0; g4 < 8; ++g4) {
                const float4 v = kr[g4];
                const float2 a = fk[g4*4+0], b2 = fk[g4*4+1], c = fk[g4*4+2], d = fk[g4*4+3];
                re += v.x * a.x + v.y * b2.x + v.z * c.x + v.w * d.x;
                im += v.x * a.y + v.y * b2.y + v.z * c.y + v.w * d.y;
            }
            psic[(o * NSPEC + s) * F_IN + i] = make_float2(re * SCALING, im * SCALING);
        }
    } else if (blk < 627) {
        // ---- wigt4[kc][p4] (+ p4lut when kc==0) ----
        const int t = (blk - 512) * 256 + tid;
        if (t < NP4 * 8) {
            const int p4 = t >> 3, kc = t & 7;
            int l, m, n, valid;
            decode_p4(p4, l, m, n, valid);
            const int wo = d_cof2[l] + m * (2 * l + 1) + n;
            float4 v = make_float4(0.f, 0.f, 0.f, 0.f);
            if (valid) {
                v.x = wig[(kc * 4 + 0) * 5456 + wo];
                v.y = wig[(kc * 4 + 1) * 5456 + wo];
                v.z = wig[(kc * 4 + 2) * 5456 + wo];
                v.w = wig[(kc * 4 + 3) * 5456 + wo];
            }
            wigt4[(size_t)kc * NP4 + p4] = v;
            if (kc == 0) {
                const int u  = l * (l + 1) / 2 + m;
                const int sn = l * l + l + n;
                p4lut[p4] = (unsigned)u | ((unsigned)sn << 8) | ((unsigned)valid << 16);
            }
        }
    } else {
        // ---- itemlut[t]: O4 | m<<12 | nn<<16 | nq<<21 ----
        const int t = (blk - 627) * 256 + tid;
        if (t < NITEMS) {
            int lam, r, m, n;
            decode_item(t, lam, r, m, n);
            const int pl = (19 - lam) & ~3;
            const int O4 = d_PB[lam] + r * pl;
            const int nq = pl >> 2;
            itemlut[t] = (unsigned)O4 | ((unsigned)m << 12) | ((unsigned)(n + 15) << 16) | ((unsigned)nq << 21);
        }
    }
}

// ---------------- K3b fused: per bo: stage ps -> fz into LDS -> loop kc {S -> G -> out} ----------------
__global__ __launch_bounds__(256) void k3b_fused(const float2* __restrict__ fhat,
                                                 const float2* __restrict__ psic,
                                                 const float4* __restrict__ wigt4,
                                                 const unsigned int* __restrict__ p4lut,
                                                 const unsigned int* __restrict__ itemlut,
                                                 const float* __restrict__ bias,
                                                 float* __restrict__ out) {
    __shared__ __align__(16) float2 fzL[NP4Q];       // 31280 B, swizzled q = p + (p>>4)
    __shared__ __align__(16) char sgbuf[36864];      // ps[256][18] staging, then S+G
    __shared__ float2 tw[32];
    const int bo = blockIdx.x;
    const int b = bo >> 6, o = bo & 63;
    const int tid = threadIdx.x;
    const float bb = bias[o];

    if (tid < 32) {
        float s_, c_;
        sincosf(W32 * (float)tid, &s_, &c_);
        tw[tid] = make_float2(c_, s_);
    }

    // ---- stage psic panel into sgbuf as [256][18] (pad 18 to spread banks) ----
    float2* psL = (float2*)sgbuf;
    {
        const float4* src = (const float4*)(psic + (size_t)o * NSPEC * F_IN);  // 2048 float4
        for (int t = tid; t < 2048; t += 256) {
            const int row = t >> 3, c4 = t & 7;
            *(float4*)(psL + row * 18 + c4 * 2) = src[t];
        }
    }
    __syncthreads();

    // ---- fz compute into fzL (swizzled) ----
    {
        const float2* fhb = fhat + (size_t)b * NU * F_IN;
        for (int p = tid; p < NP4; p += 256) {
            const unsigned e = p4lut[p];
            float2 v = make_float2(0.f, 0.f);
            if (e >> 16) {
                const int u = e & 255, sn = (e >> 8) & 255;
                const float4* A4 = (const float4*)(fhb + u * 16);
                const float4* C4 = (const float4*)(psL + sn * 18);
                float re = 0.f, im = 0.f;
                #pragma unroll
                for (int i2 = 0; i2 < 8; ++i2) {
                    const float4 A = A4[i2], C = C4[i2];
                    re += A.x*C.x - A.y*C.y + A.z*C.z - A.w*C.w;
                    im += A.x*C.y + A.y*C.x + A.z*C.w + A.w*C.z;
                }
                v = make_float2(re, im);
            }
            fzL[p + (p >> 4)] = v;
        }
    }
    __syncthreads();

    float2 (*S)[16][33] = (float2 (*)[16][33])sgbuf;             // 16896 B
    float2 (*G)[16][33] = (float2 (*)[16][33])(sgbuf + 16896);   // 16896 B

    for (int kc = 0; kc < 8; ++kc) {
        const float4* wtb = wigt4 + (size_t)kc * NP4;

        // ----- S-stage: 496 items; fz from LDS, wigt4 from L2 -----
        #pragma unroll
        for (int it = 0; it < 2; ++it) {
            const int t = tid + it * 256;
            if (t < NITEMS) {
                const unsigned e = itemlut[t];
                const int O4 = e & 0xFFF, m = (e >> 12) & 15, nn = (e >> 16) & 31, nq = (e >> 21) & 7;
                const float4* wt = wtb + O4;
                float sr0=0,si0=0,sr1=0,si1=0,sr2=0,si2=0,sr3=0,si3=0;
                int idx = O4;
                for (int c = 0; c < nq; ++c) {
                    #pragma unroll
                    for (int j = 0; j < 4; ++j) {
                        const int q = idx + j;
                        const float2 z = fzL[q + (q >> 4)];
                        const float4 w = wt[c * 4 + j];
                        sr0 += z.x * w.x; si0 += z.y * w.x;
                        sr1 += z.x * w.y; si1 += z.y * w.y;
                        sr2 += z.x * w.z; si2 += z.y * w.z;
                        sr3 += z.x * w.w; si3 += z.y * w.w;
                    }
                    idx += 4;
                }
                S[0][m][nn] = make_float2(sr0, si0);
                S[1][m][nn] = make_float2(sr1, si1);
                S[2][m][nn] = make_float2(sr2, si2);
                S[3][m][nn] = make_float2(sr3, si3);
            }
        }
        __syncthreads();

        // ----- G-phase: G[kk][m][g] = sum_n S[kk][m][n] e^{i n g w} -----
        {
            const int kk = tid >> 6, m = (tid >> 2) & 15, g0 = tid & 3;
            float ar[4] = {0,0,0,0}, ai[4] = {0,0,0,0}, br[4] = {0,0,0,0}, bi[4] = {0,0,0,0};
            const float2* Srow = &S[kk][m][0];
            #pragma unroll
            for (int nn = 0; nn < 31; ++nn) {
                const float2 sv = Srow[nn];
                const int n = nn - 15;
                #pragma unroll
                for (int q = 0; q < 4; ++q) {
                    const int g = g0 + 4 * q;
                    const float2 w = tw[(n * g) & 31];
                    const float X = sv.x * w.x - sv.y * w.y;
                    const float Y = sv.x * w.y + sv.y * w.x;
                    ar[q] += X; ai[q] += Y;
                    if (nn & 1) { br[q] += X; bi[q] += Y; }   // n even
                    else        { br[q] -= X; bi[q] -= Y; }   // n odd: e^{i n pi} = -1
                }
            }
            #pragma unroll
            for (int q = 0; q < 4; ++q) {
                const int g = g0 + 4 * q;
                G[kk][m][g]      = make_float2(ar[q], ai[q]);
                G[kk][m][g + 16] = make_float2(br[q], bi[q]);
            }
        }
        __syncthreads();

        // ----- out-phase: direct global stores -----
        {
            const int kk = tid >> 6, g = tid & 31, a0 = (tid >> 5) & 1;
            const float base = G[kk][0][g].x + bb;
            float o_[4][4];
            #pragma unroll
            for (int rep = 0; rep < 4; ++rep)
                #pragma unroll
                for (int j = 0; j < 4; ++j) o_[rep][j] = base;
            #pragma unroll
            for (int m = 1; m < 16; ++m) {
                const float2 gv = G[kk][m][g];
                const float gx = 2.f * gv.x, gy = 2.f * gv.y;
                #pragma unroll
                for (int rep = 0; rep < 4; ++rep) {
                    const int A = a0 + 2 * rep;
                    const float2 w = tw[(m * A) & 31];
                    const float X = gx * w.x - gy * w.y;
                    const float Y = gx * w.y + gy * w.x;
                    o_[rep][0] += X;
                    o_[rep][1] += ((m & 3) == 1) ? -Y : ((m & 3) == 2) ? -X : ((m & 3) == 3) ? Y : X;
                    o_[rep][2] += (m & 1) ? -X : X;
                    o_[rep][3] += ((m & 3) == 1) ? Y : ((m & 3) == 2) ? -X : ((m & 3) == 3) ? -Y : X;
                }
            }
            float* ob = out + (((size_t)bo << 15) + ((size_t)(kc * 4 + kk) << 10));
            #pragma unroll
            for (int rep = 0; rep < 4; ++rep) {
                #pragma unroll
                for (int j = 0; j < 4; ++j) {
                    const int a = a0 + 2*rep + 8*j;
                    ob[(a << 5) + g] = o_[rep][j];
                }
            }
        }
        // next iteration's S-write is fenced from this kc's G-reads by the barrier
        // after the S-stage; out-phase reads G which next S-write doesn't touch.
    }
}

extern "C" void kernel_launch(void* const* d_in, const int* in_sizes, int n_in,
                              void* d_out, int out_size, void* d_ws, size_t ws_size,
                              hipStream_t stream) {
    const float* x       = (const float*)d_in[0];
    const float* kern    = (const float*)d_in[1];
    const float* bias    = (const float*)d_in[2];
    const float* wig_s2  = (const float*)d_in[3];
    const float* fk_re   = (const float*)d_in[4];
    const float* fk_im   = (const float*)d_in[5];
    const float* wig_so3 = (const float*)d_in[6];
    float* out = (float*)d_out;

    // ws layout (fzp4 eliminated)
    float2*       fhat_t  = (float2*)d_ws;                              // 16*136*16*8 = 278528
    float2*       psic_t  = (float2*)((char*)d_ws + 327680);            // 64*256*16*8 = 2097152
    float4*       wigt4   = (float4*)((char*)d_ws + 2424832);           // 8*3680*16   = 470720
    unsigned int* p4lut   = (unsigned int*)((char*)d_ws + 2895872);     // 3680*4      = 14720
    unsigned int* itemlut = (unsigned int*)((char*)d_ws + 2910592);     // 496*4       = 1984

    k_prep<<<629, 256, 0, stream>>>(x, wig_s2, kern, fk_re, fk_im, wig_so3,
                                    fhat_t, psic_t, wigt4, p4lut, itemlut);
    k3b_fused<<<BATCH * F_OUT, 256, 0, stream>>>(fhat_t, psic_t, wigt4, p4lut, itemlut, bias, out);
}